// Round 17
// baseline (369.368 us; speedup 1.0000x reference)
//
#include <hip/hip_runtime.h>
#include <hip/hip_bf16.h>
#include <hip/hip_fp8.h>

typedef __attribute__((ext_vector_type(8))) short short8;
typedef __attribute__((ext_vector_type(4))) short short4_t;
typedef __attribute__((ext_vector_type(4))) float floatx4;
typedef __attribute__((ext_vector_type(2))) float floatx2;

constexpr int NB  = 256;    // dst buckets
constexpr int CAP = 6144;   // pairs per bucket (mean 4096 for uniform graph)

__device__ __forceinline__ unsigned short f2bf(float f){
  unsigned int u = __float_as_uint(f);
  u += 0x7FFF + ((u >> 16) & 1);           // RNE
  return (unsigned short)(u >> 16);
}
__device__ __forceinline__ float bf2f(unsigned short h){
  return __uint_as_float(((unsigned int)h) << 16);
}
__device__ __forceinline__ float lrelu(float x){ return x > 0.f ? x : 0.2f * x; }
__device__ __forceinline__ float eluf(float x){ return x > 0.f ? x : (__expf(x) - 1.f); }

__device__ __forceinline__ unsigned char f2fp8(float f){
  __hip_fp8_e4m3 t(f);
  return (unsigned char)t.__x;
}
__device__ __forceinline__ float fp82f(unsigned char b){
  __hip_fp8_e4m3 t;
  t.__x = (__hip_fp8_storage_t)b;
  return (float)t;
}

template<bool HI>
__device__ __forceinline__ floatx2 fp8pk2(unsigned int v){
#if defined(__has_builtin) && __has_builtin(__builtin_amdgcn_cvt_pk_f32_fp8)
  return __builtin_amdgcn_cvt_pk_f32_fp8((int)v, HI);
#else
  floatx2 r;
  constexpr int sh = HI ? 16 : 0;
  r.x = fp82f((unsigned char)((v >> sh) & 0xFF));
  r.y = fp82f((unsigned char)((v >> (sh + 8)) & 0xFF));
  return r;
#endif
}

// HW packed fp8 encode of 4 floats -> 4 bytes (returned in uint, b0..b3)
__device__ __forceinline__ unsigned int f32x4_to_fp8(float a0, float a1, float a2, float a3){
#if defined(__has_builtin) && __has_builtin(__builtin_amdgcn_cvt_pk_fp8_f32)
  int w = 0;
  w = __builtin_amdgcn_cvt_pk_fp8_f32(a0, a1, w, false);   // bytes 0,1
  w = __builtin_amdgcn_cvt_pk_fp8_f32(a2, a3, w, true);    // bytes 2,3
  return (unsigned int)w;
#else
  return (unsigned int)f2fp8(a0) | ((unsigned int)f2fp8(a1) << 8) |
         ((unsigned int)f2fp8(a2) << 16) | ((unsigned int)f2fp8(a3) << 24);
#endif
}

// async global->LDS, 16B per lane; LDS dest = base + lane*16
__device__ __forceinline__ void gload16(const unsigned short* g, unsigned short* l){
  __builtin_amdgcn_global_load_lds(
      (const __attribute__((address_space(1))) unsigned int*)(const void*)g,
      (__attribute__((address_space(3))) unsigned int*)(void*)l,
      16, 0, 0);
}

// ---------------- CSR build: two-level bucket sort (LDS-local random access) ----------------

__global__ __launch_bounds__(256) void part_k(const int* __restrict__ ei, int E, int shift,
                                              int* __restrict__ gcnt,
                                              uint2* __restrict__ bbuf){
  __shared__ int hist[NB];
  __shared__ int base[NB];
  int tid = threadIdx.x;
  hist[tid] = 0;
  __syncthreads();
  int blk_start = blockIdx.x * 4096;
  int src[16], bkt[16], lp[16];
  #pragma unroll
  for (int k = 0; k < 16; k++){
    int i = blk_start + k * 256 + tid;
    if (i < E){
      int dst = ei[E + i];
      src[k] = ei[i];
      bkt[k] = dst >> shift;
      lp[k] = atomicAdd(&hist[bkt[k]], 1);
    } else {
      bkt[k] = -1;
    }
  }
  __syncthreads();
  base[tid] = atomicAdd(&gcnt[tid], hist[tid]);
  __syncthreads();
  #pragma unroll
  for (int k = 0; k < 16; k++){
    int i = blk_start + k * 256 + tid;
    if (i < E){
      int b = bkt[k];
      int dst = ei[E + i];              // re-read dst (L2 hot)
      bbuf[(size_t)b * CAP + base[b] + lp[k]] = make_uint2((unsigned)src[k], (unsigned)dst);
    }
  }
}

__global__ __launch_bounds__(256) void bscan_k(const int* __restrict__ gcnt,
                                               int* __restrict__ gbase,
                                               int* __restrict__ row_ptr, int N, int dpb){
  __shared__ int s[NB];
  int t = threadIdx.x;
  int v = gcnt[t] + dpb;
  s[t] = v;
  __syncthreads();
  #pragma unroll
  for (int off = 1; off < NB; off <<= 1){
    int u = (t >= off) ? s[t - off] : 0;
    __syncthreads();
    s[t] += u;
    __syncthreads();
  }
  gbase[t] = s[t] - v;
  if (t == NB - 1){ gbase[NB] = s[t]; row_ptr[N] = s[t]; }
}

// one block per bucket; counting sort fully in LDS; emits sorted_src AND sorted_dst
__global__ __launch_bounds__(256) void sort_k(const uint2* __restrict__ bbuf,
                                              const int* __restrict__ gcnt,
                                              const int* __restrict__ gbase,
                                              int* __restrict__ row_ptr,
                                              int* __restrict__ sorted_src,
                                              int* __restrict__ sorted_dst, int dpb){
  __shared__ int counts[512];
  __shared__ int curs[512];
  __shared__ int wsum[256];
  __shared__ int sortedL[CAP + 512];
  __shared__ int dstL[CAP + 512];
  int b = blockIdx.x, tid = threadIdx.x;
  int cnt = gcnt[b];
  int dstBase = b * dpb;
  int gb = gbase[b];
  counts[tid] = 0;
  counts[tid + 256] = 0;
  __syncthreads();
  for (int i = tid; i < cnt; i += 256){
    uint2 p = bbuf[(size_t)b * CAP + i];
    atomicAdd(&counts[(int)p.y - dstBase], 1);
  }
  __syncthreads();
  int c0 = counts[2 * tid] + 1;
  int c1 = counts[2 * tid + 1] + 1;
  int sum = c0 + c1;
  wsum[tid] = sum;
  __syncthreads();
  #pragma unroll
  for (int off = 1; off < 256; off <<= 1){
    int u = (tid >= off) ? wsum[tid - off] : 0;
    __syncthreads();
    wsum[tid] += u;
    __syncthreads();
  }
  int ex = wsum[tid] - sum;
  int ro0 = ex, ro1 = ex + c0;
  curs[2 * tid] = ro0 + 1;          // slot ro reserved for self-loop
  curs[2 * tid + 1] = ro1 + 1;
  sortedL[ro0] = dstBase + 2 * tid;
  sortedL[ro1] = dstBase + 2 * tid + 1;
  dstL[ro0] = dstBase + 2 * tid;
  dstL[ro1] = dstBase + 2 * tid + 1;
  row_ptr[dstBase + 2 * tid] = gb + ro0;
  row_ptr[dstBase + 2 * tid + 1] = gb + ro1;
  __syncthreads();
  for (int i = tid; i < cnt; i += 256){
    uint2 p = bbuf[(size_t)b * CAP + i];
    int pos = atomicAdd(&curs[(int)p.y - dstBase], 1);
    sortedL[pos] = (int)p.x;
    dstL[pos] = (int)p.y;
  }
  __syncthreads();
  int tot = cnt + dpb;
  for (int i = tid; i < tot; i += 256){
    sorted_src[gb + i] = sortedL[i];
    sorted_dst[gb + i] = dstL[i];
  }
}

// ---------------- edge weights for conv2: ew[e] = float4 per-head exp(lrelu(as[s]+ad[d])) ----------------
// edges sorted by dst -> ad4[d] reads sequential/L1-hot; as4[s] random 16B gather (L2)
__global__ __launch_bounds__(256) void ew4_k(const int* __restrict__ ss,
                                             const int* __restrict__ sd,
                                             const float4* __restrict__ as4,
                                             const float4* __restrict__ ad4,
                                             float4* __restrict__ ew, int tot){
  int e = blockIdx.x * 256 + threadIdx.x;
  if (e < tot){
    float4 a = as4[ss[e]];
    float4 b = ad4[sd[e]];
    float4 o;
    o.x = __expf(lrelu(a.x + b.x));
    o.y = __expf(lrelu(a.y + b.y));
    o.z = __expf(lrelu(a.z + b.z));
    o.w = __expf(lrelu(a.w + b.w));
    ew[e] = o;
  }
}

// ---------------- fused prep: pack W2/W3 + conv1 tables ----------------

__global__ __launch_bounds__(256) void prep_k(const float* __restrict__ W2,
                                              unsigned short* __restrict__ Wp2,
                                              const float* __restrict__ W3,
                                              unsigned short* __restrict__ Wp3,
                                              const float* __restrict__ emb,
                                              const float* __restrict__ W1,
                                              const float* __restrict__ a1s,
                                              const float* __restrict__ a1d,
                                              float* __restrict__ T1,
                                              float* __restrict__ wt_tab){
  __shared__ float t_lds[1280];
  __shared__ float as_l[20], ad_l[20];
  int b = blockIdx.x;
  int tid = threadIdx.x;
  if (b < 256){                      // W2 [256,256] -> Wp2[n*256+k]
    int idx = b * 256 + tid;
    int k = idx >> 8, nn = idx & 255;
    Wp2[nn * 256 + k] = f2bf(W2[idx]);
  } else if (b < 320){               // W3 [256,64] -> Wp3[n*256+k]
    int idx = (b - 256) * 256 + tid;
    int k = idx >> 6, nn = idx & 63;
    Wp3[nn * 256 + k] = f2bf(W3[idx]);
  } else {                           // table1
    for (int i = tid; i < 1280; i += 256){
      int r = i >> 8, c = i & 255;
      float s = 0.f;
      for (int k = 0; k < 64; k++) s += emb[r * 64 + k] * W1[k * 256 + c];
      t_lds[i] = s;
      T1[i] = s;
    }
    __syncthreads();
    if (tid < 20){
      int r = tid >> 2, hh = tid & 3;
      float ss = 0.f, sd = 0.f;
      for (int c = 0; c < 64; c++){
        float f = t_lds[r * 256 + hh * 64 + c];
        ss += f * a1s[hh * 64 + c];
        sd += f * a1d[hh * 64 + c];
      }
      as_l[tid] = ss;
      ad_l[tid] = sd;
    }
    __syncthreads();
    if (tid < 100){
      int xd = tid / 20, rest = tid % 20;      // rest = xs*4+h
      int h = rest & 3;
      wt_tab[tid] = __expf(lrelu(as_l[rest] + ad_l[xd * 4 + h]));
    }
  }
}

// ---------------- LDS-staged MFMA GEMM, fused alpha epilogues ----------------
// MODE 1 (BN=128): per-head alpha. MODE 2 (BN=64): scalar alpha.
// F8OUT: C written as fp8 e4m3 scaled x64.
// SWZ: 1D grid; (x,y=0)/(x,y=1) placed 8 block-slots apart -> same XCD -> A-tile L2 reuse.
template<int BN, int MODE, bool F8OUT, bool SWZ>
__global__ __launch_bounds__(256) void gemm_lds_k(const unsigned short* __restrict__ A,
                                                  const unsigned short* __restrict__ Wp,
                                                  void* __restrict__ Cout, int Nc,
                                                  const float* __restrict__ a_src,
                                                  const float* __restrict__ a_dst,
                                                  float* __restrict__ as_arr,
                                                  float* __restrict__ ad_arr){
  constexpr int K = 256;
  constexpr int NT = BN / 32;               // col tiles per wave (4 or 2)
  __shared__ unsigned short Alds[128 * 32];
  __shared__ unsigned short Blds[BN * 32];
  __shared__ float asl[128], adl[128];
  __shared__ float pas[128][2], pad[128][2];
  int tid = threadIdx.x;
  int w = tid >> 6, l = tid & 63;
  int r16 = l & 15, quad = l >> 4;
  int wr = w >> 1, wc = w & 1;
  int bx, by;
  if constexpr (SWZ){
    int b = blockIdx.x;
    int g = b >> 4, i = b & 15;
    bx = g * 8 + (i & 7);
    by = i >> 3;
  } else {
    bx = blockIdx.x;
    by = blockIdx.y;
  }
  int mBase = bx * 128;
  int nBase = by * BN;

  if constexpr (MODE == 1){
    if (tid < 128){ asl[tid] = a_src[nBase + tid]; adl[tid] = a_dst[nBase + tid]; }
  }
  if constexpr (MODE == 2){
    if (tid < 64){ asl[tid] = a_src[tid]; adl[tid] = a_dst[tid]; }
  }

  int arow = l >> 2;
  int kcol = (l & 3) * 8;                   // shorts
  const unsigned short* gA0 = A + (size_t)(mBase + w * 32 + arow) * K + kcol;
  const unsigned short* gA1 = gA0 + (size_t)16 * K;
  unsigned short* lA0 = &Alds[(w * 32) * 32];
  unsigned short* lA1 = &Alds[(w * 32 + 16) * 32];
  const unsigned short* gB0;
  const unsigned short* gB1 = nullptr;
  unsigned short* lB0;
  unsigned short* lB1 = nullptr;
  if constexpr (BN == 128){
    gB0 = Wp + (size_t)(nBase + w * 32 + arow) * K + kcol;
    gB1 = gB0 + (size_t)16 * K;
    lB0 = &Blds[(w * 32) * 32];
    lB1 = &Blds[(w * 32 + 16) * 32];
  } else {
    gB0 = Wp + (size_t)(nBase + w * 16 + arow) * K + kcol;
    lB0 = &Blds[(w * 16) * 32];
  }

  floatx4 acc[4][NT];
  #pragma unroll
  for (int mt = 0; mt < 4; mt++)
    #pragma unroll
    for (int nt = 0; nt < NT; nt++){ floatx4 z = {0.f,0.f,0.f,0.f}; acc[mt][nt] = z; }

  for (int kt = 0; kt < 8; kt++){
    int ko = kt * 32;
    gload16(gA0 + ko, lA0);
    gload16(gA1 + ko, lA1);
    gload16(gB0 + ko, lB0);
    if constexpr (BN == 128) gload16(gB1 + ko, lB1);
    __syncthreads();
    short8 af[4], bfr[NT];
    #pragma unroll
    for (int mt = 0; mt < 4; mt++)
      af[mt] = *(const short8*)&Alds[(wr * 64 + mt * 16 + r16) * 32 + quad * 8];
    #pragma unroll
    for (int nt = 0; nt < NT; nt++)
      bfr[nt] = *(const short8*)&Blds[(wc * (BN / 2) + nt * 16 + r16) * 32 + quad * 8];
    #pragma unroll
    for (int mt = 0; mt < 4; mt++)
      #pragma unroll
      for (int nt = 0; nt < NT; nt++)
        acc[mt][nt] = __builtin_amdgcn_mfma_f32_16x16x32_bf16(af[mt], bfr[nt], acc[mt][nt], 0, 0, 0);
    __syncthreads();
  }

  // epilogue: C/D layout col=lane&15, row=quad*4+reg
  #pragma unroll
  for (int mt = 0; mt < 4; mt++){
    #pragma unroll
    for (int nt = 0; nt < NT; nt++){
      if constexpr (F8OUT){
        unsigned int pk = f32x4_to_fp8(acc[mt][nt][0] * 64.f, acc[mt][nt][1] * 64.f,
                                       acc[mt][nt][2] * 64.f, acc[mt][nt][3] * 64.f);
        int col = nBase + wc * (BN / 2) + nt * 16 + r16;
        int row0 = mBase + wr * 64 + mt * 16 + quad * 4;
        #pragma unroll
        for (int r = 0; r < 4; r++)
          ((unsigned char*)Cout)[(size_t)(row0 + r) * Nc + col] =
              (unsigned char)((pk >> (r * 8)) & 0xFF);
      } else {
        #pragma unroll
        for (int r = 0; r < 4; r++){
          int row = mBase + wr * 64 + mt * 16 + quad * 4 + r;
          int col = nBase + wc * (BN / 2) + nt * 16 + r16;
          ((unsigned short*)Cout)[(size_t)row * Nc + col] = f2bf(acc[mt][nt][r]);
        }
      }
    }
  }
  if constexpr (MODE == 1){
    int head = (nBase + wc * 64) >> 6;
    #pragma unroll
    for (int mt = 0; mt < 4; mt++){
      #pragma unroll
      for (int r = 0; r < 4; r++){
        float ps = 0.f, pd = 0.f;
        #pragma unroll
        for (int nt = 0; nt < NT; nt++){
          float v = acc[mt][nt][r];
          int ci = wc * 64 + nt * 16 + r16;
          ps += v * asl[ci];
          pd += v * adl[ci];
        }
        ps += __shfl_xor(ps, 1, 64); ps += __shfl_xor(ps, 2, 64);
        ps += __shfl_xor(ps, 4, 64); ps += __shfl_xor(ps, 8, 64);
        pd += __shfl_xor(pd, 1, 64); pd += __shfl_xor(pd, 2, 64);
        pd += __shfl_xor(pd, 4, 64); pd += __shfl_xor(pd, 8, 64);
        if (r16 == 0){
          int row = mBase + wr * 64 + mt * 16 + quad * 4 + r;
          as_arr[row * 4 + head] = ps;
          ad_arr[row * 4 + head] = pd;
        }
      }
    }
  }
  if constexpr (MODE == 2){
    #pragma unroll
    for (int mt = 0; mt < 4; mt++){
      #pragma unroll
      for (int r = 0; r < 4; r++){
        float ps = 0.f, pd = 0.f;
        #pragma unroll
        for (int nt = 0; nt < NT; nt++){
          float v = acc[mt][nt][r];
          int ci = wc * 32 + nt * 16 + r16;
          ps += v * asl[ci];
          pd += v * adl[ci];
        }
        ps += __shfl_xor(ps, 1, 64); ps += __shfl_xor(ps, 2, 64);
        ps += __shfl_xor(ps, 4, 64); ps += __shfl_xor(ps, 8, 64);
        pd += __shfl_xor(pd, 1, 64); pd += __shfl_xor(pd, 2, 64);
        pd += __shfl_xor(pd, 4, 64); pd += __shfl_xor(pd, 8, 64);
        if (r16 == 0){
          int lr = wr * 64 + mt * 16 + quad * 4 + r;
          pas[lr][wc] = ps;
          pad[lr][wc] = pd;
        }
      }
    }
    __syncthreads();
    if (tid < 128){
      as_arr[mBase + tid] = pas[tid][0] + pas[tid][1];
      ad_arr[mBase + tid] = pad[tid][0] + pad[tid][1];
    }
  }
}

// ---------------- conv1 aggregation: 5-bin neighbor-value histogram ----------------

__global__ __launch_bounds__(256) void agg1_k(const int* __restrict__ x,
                                              const float* __restrict__ T1,
                                              const float* __restrict__ wt_tab,
                                              const int* __restrict__ row_ptr,
                                              const int* __restrict__ sorted_src,
                                              const float* __restrict__ bias,
                                              unsigned short* __restrict__ outb){
  __shared__ float t_lds[1280];
  __shared__ float wt_l[100], b_lds[256];
  __shared__ float cnt_lds[256][5];
  __shared__ int xd_lds[256];
  int tid = threadIdx.x;
  for (int i = tid; i < 1280; i += 256) t_lds[i] = T1[i];
  if (tid < 100) wt_l[tid] = wt_tab[tid];
  b_lds[tid] = bias[tid];
  // phase 1: histogram
  int d = blockIdx.x * 256 + tid;
  int start = row_ptr[d], end = row_ptr[d + 1];
  xd_lds[tid] = x[d];
  float c0 = 0.f, c1 = 0.f, c2 = 0.f, c3 = 0.f, c4 = 0.f;
  for (int e = start; e < end; e++){
    int xs = x[sorted_src[e]];
    c0 += (xs == 0) ? 1.f : 0.f;
    c1 += (xs == 1) ? 1.f : 0.f;
    c2 += (xs == 2) ? 1.f : 0.f;
    c3 += (xs == 3) ? 1.f : 0.f;
    c4 += (xs == 4) ? 1.f : 0.f;
  }
  cnt_lds[tid][0] = c0; cnt_lds[tid][1] = c1; cnt_lds[tid][2] = c2;
  cnt_lds[tid][3] = c3; cnt_lds[tid][4] = c4;
  __syncthreads();
  // phase 2: wave per dst, lane covers 4 channels
  int w = tid >> 6, l = tid & 63;
  int head = l >> 4;
  int c0i = l * 4;
  for (int dl = w; dl < 256; dl += 4){
    int dd = blockIdx.x * 256 + dl;
    int xd20 = xd_lds[dl] * 20;
    float ws[5];
    float den = 0.f;
    #pragma unroll
    for (int v2 = 0; v2 < 5; v2++){
      float wv = wt_l[xd20 + v2 * 4 + head] * cnt_lds[dl][v2];
      ws[v2] = wv;
      den += wv;
    }
    float inv = 1.f / (den + 1e-16f);
    float num[4] = {0.f, 0.f, 0.f, 0.f};
    #pragma unroll
    for (int v2 = 0; v2 < 5; v2++){
      const float4 row = *(const float4*)&t_lds[v2 * 256 + c0i];
      num[0] += ws[v2] * row.x;
      num[1] += ws[v2] * row.y;
      num[2] += ws[v2] * row.z;
      num[3] += ws[v2] * row.w;
    }
    short4_t ov;
    #pragma unroll
    for (int j = 0; j < 4; j++)
      ov[j] = (short)f2bf(eluf(num[j] * inv + b_lds[c0i + j]));
    *(short4_t*)(outb + (size_t)dd * 256 + c0i) = ov;
  }
}

// ---------------- conv2 aggregation: 4-deep unrolled gather, fp8 payload, precomputed ew ----------------

__global__ __launch_bounds__(256) void agg4_k(const unsigned char* __restrict__ h8,
                                              const float* __restrict__ ewf,
                                              const int* __restrict__ row_ptr,
                                              const int* __restrict__ sorted_src,
                                              const float* __restrict__ bias,
                                              unsigned short* __restrict__ outb){
  __shared__ float b_lds[256];
  int tid = threadIdx.x;
  b_lds[tid] = bias[tid];
  __syncthreads();
  int w = tid >> 6, l = tid & 63;
  int d = blockIdx.x * 4 + w;
  int hl = l & 31, half = l >> 5;
  unsigned head = (unsigned)(hl >> 3);
  unsigned hloff = (unsigned)(hl * 8);
  int start = row_ptr[d], end = row_ptr[d + 1];
  floatx2 ac0 = {0.f, 0.f}, ac1 = {0.f, 0.f}, ac2 = {0.f, 0.f}, ac3 = {0.f, 0.f};
  float den = 0.f;
  int e = start + half;
  for (; e + 6 < end; e += 8){
    unsigned sA = (unsigned)sorted_src[e];
    unsigned sB = (unsigned)sorted_src[e + 2];
    unsigned sC = (unsigned)sorted_src[e + 4];
    unsigned sD = (unsigned)sorted_src[e + 6];
    uint2 vA = *(const uint2*)(h8 + ((sA << 8) | hloff));
    uint2 vB = *(const uint2*)(h8 + ((sB << 8) | hloff));
    uint2 vC = *(const uint2*)(h8 + ((sC << 8) | hloff));
    uint2 vD = *(const uint2*)(h8 + ((sD << 8) | hloff));
    float wgA = ewf[((unsigned)e << 2) + head];
    float wgB = ewf[(((unsigned)e + 2) << 2) + head];
    float wgC = ewf[(((unsigned)e + 4) << 2) + head];
    float wgD = ewf[(((unsigned)e + 6) << 2) + head];
    den += (wgA + wgB) + (wgC + wgD);
    floatx2 wA = {wgA, wgA}, wB = {wgB, wgB}, wC = {wgC, wgC}, wD = {wgD, wgD};
    ac0 += wA * fp8pk2<false>(vA.x) + wB * fp8pk2<false>(vB.x)
         + wC * fp8pk2<false>(vC.x) + wD * fp8pk2<false>(vD.x);
    ac1 += wA * fp8pk2<true>(vA.x)  + wB * fp8pk2<true>(vB.x)
         + wC * fp8pk2<true>(vC.x)  + wD * fp8pk2<true>(vD.x);
    ac2 += wA * fp8pk2<false>(vA.y) + wB * fp8pk2<false>(vB.y)
         + wC * fp8pk2<false>(vC.y) + wD * fp8pk2<false>(vD.y);
    ac3 += wA * fp8pk2<true>(vA.y)  + wB * fp8pk2<true>(vB.y)
         + wC * fp8pk2<true>(vC.y)  + wD * fp8pk2<true>(vD.y);
  }
  for (; e < end; e += 2){
    unsigned s = (unsigned)sorted_src[e];
    float wg = ewf[((unsigned)e << 2) + head];
    den += wg;
    uint2 v = *(const uint2*)(h8 + ((s << 8) | hloff));
    floatx2 wv = {wg, wg};
    ac0 += wv * fp8pk2<false>(v.x);
    ac1 += wv * fp8pk2<true>(v.x);
    ac2 += wv * fp8pk2<false>(v.y);
    ac3 += wv * fp8pk2<true>(v.y);
  }
  float acc[8] = {ac0.x, ac0.y, ac1.x, ac1.y, ac2.x, ac2.y, ac3.x, ac3.y};
  #pragma unroll
  for (int j = 0; j < 8; j++) acc[j] += __shfl_xor(acc[j], 32, 64);
  den += __shfl_xor(den, 32, 64);
  if (half == 0){
    float inv = 0.015625f / (den + 1e-16f);    // 1/64 undoes fp8 pre-scale
    short8 ov;
    #pragma unroll
    for (int j = 0; j < 8; j++){
      float v = eluf(acc[j] * inv + b_lds[hl * 8 + j]);
      ov[j] = (short)f2bf(v);
    }
    *(short8*)(outb + (size_t)d * 256 + hl * 8) = ov;
  }
}

// ---------------- conv3 aggregation (H=1): fp8 payload, eighth-wave per edge ----------------

__global__ __launch_bounds__(256) void agg3_k(const unsigned char* __restrict__ h8,
                                              const float* __restrict__ as_arr,
                                              const float* __restrict__ ad_arr,
                                              const int* __restrict__ row_ptr,
                                              const int* __restrict__ sorted_src,
                                              const float* __restrict__ bias,
                                              unsigned short* __restrict__ outb){
  __shared__ float b_lds[64];
  int tid = threadIdx.x;
  if (tid < 64) b_lds[tid] = bias[tid];
  __syncthreads();
  int w = tid >> 6, l = tid & 63;
  int d = blockIdx.x * 4 + w;
  int q = l & 7, grp = l >> 3;          // 8 groups of 8 lanes
  unsigned qoff = (unsigned)(q * 8);    // 8 bytes per lane
  int start = row_ptr[d], end = row_ptr[d + 1];
  float a_d = ad_arr[d];
  floatx2 ac0 = {0.f, 0.f}, ac1 = {0.f, 0.f}, ac2 = {0.f, 0.f}, ac3 = {0.f, 0.f};
  float den = 0.f;
  int e = start + grp;
  for (; e + 8 < end; e += 16){
    unsigned sA = (unsigned)sorted_src[e];
    unsigned sB = (unsigned)sorted_src[e + 8];
    uint2 vA = *(const uint2*)(h8 + ((sA << 6) | qoff));
    uint2 vB = *(const uint2*)(h8 + ((sB << 6) | qoff));
    float wgA = __expf(lrelu(as_arr[sA] + a_d));
    float wgB = __expf(lrelu(as_arr[sB] + a_d));
    den += wgA + wgB;
    floatx2 wA = {wgA, wgA}, wB = {wgB, wgB};
    ac0 += wA * fp8pk2<false>(vA.x) + wB * fp8pk2<false>(vB.x);
    ac1 += wA * fp8pk2<true>(vA.x)  + wB * fp8pk2<true>(vB.x);
    ac2 += wA * fp8pk2<false>(vA.y) + wB * fp8pk2<false>(vB.y);
    ac3 += wA * fp8pk2<true>(vA.y)  + wB * fp8pk2<true>(vB.y);
  }
  for (; e < end; e += 8){
    unsigned s = (unsigned)sorted_src[e];
    float wg = __expf(lrelu(as_arr[s] + a_d));
    den += wg;
    uint2 v = *(const uint2*)(h8 + ((s << 6) | qoff));
    floatx2 wv = {wg, wg};
    ac0 += wv * fp8pk2<false>(v.x);
    ac1 += wv * fp8pk2<true>(v.x);
    ac2 += wv * fp8pk2<false>(v.y);
    ac3 += wv * fp8pk2<true>(v.y);
  }
  float acc[8] = {ac0.x, ac0.y, ac1.x, ac1.y, ac2.x, ac2.y, ac3.x, ac3.y};
  #pragma unroll
  for (int j = 0; j < 8; j++){
    acc[j] += __shfl_xor(acc[j], 8, 64);
    acc[j] += __shfl_xor(acc[j], 16, 64);
    acc[j] += __shfl_xor(acc[j], 32, 64);
  }
  den += __shfl_xor(den, 8, 64);
  den += __shfl_xor(den, 16, 64);
  den += __shfl_xor(den, 32, 64);
  if (l < 8){
    float inv = 0.015625f / (den + 1e-16f);    // 1/64 undoes fp8 pre-scale
    short8 ov;
    #pragma unroll
    for (int j = 0; j < 8; j++){
      float v = eluf(acc[j] * inv + b_lds[q * 8 + j]);
      ov[j] = (short)f2bf(v);
    }
    *(short8*)(outb + (size_t)d * 64 + q * 8) = ov;
  }
}

// ---------------- final FC: out[N,5] = h[N,64] @ fc_w + fc_b ----------------

__global__ __launch_bounds__(256) void fc_k(const unsigned short* __restrict__ hb,
                                            const float* __restrict__ fcw,
                                            const float* __restrict__ fcb,
                                            float* __restrict__ out){
  __shared__ float w_lds[320];
  __shared__ float b_lds[5];
  int tid = threadIdx.x;
  for (int i = tid; i < 320; i += 256) w_lds[i] = fcw[i];
  if (tid < 5) b_lds[tid] = fcb[tid];
  __syncthreads();
  int n = blockIdx.x * 256 + tid;
  const short8* p = (const short8*)(hb + (size_t)n * 64);
  float acc[5];
  #pragma unroll
  for (int j = 0; j < 5; j++) acc[j] = b_lds[j];
  #pragma unroll
  for (int b = 0; b < 8; b++){
    short8 v = p[b];
    #pragma unroll
    for (int j8 = 0; j8 < 8; j8++){
      float f = bf2f((unsigned short)v[j8]);
      int k = b * 8 + j8;
      #pragma unroll
      for (int j = 0; j < 5; j++) acc[j] += f * w_lds[k * 5 + j];
    }
  }
  #pragma unroll
  for (int j = 0; j < 5; j++) out[(size_t)n * 5 + j] = acc[j];
}

// ---------------- host launch ----------------

extern "C" void kernel_launch(void* const* d_in, const int* in_sizes, int n_in,
                              void* d_out, int out_size, void* d_ws, size_t ws_size,
                              hipStream_t stream){
  const int*   x    = (const int*)d_in[0];
  const int*   ei   = (const int*)d_in[1];
  const float* emb  = (const float*)d_in[2];
  const float* W1   = (const float*)d_in[3];
  const float* a1s  = (const float*)d_in[4];
  const float* a1d  = (const float*)d_in[5];
  const float* b1   = (const float*)d_in[6];
  const float* W2   = (const float*)d_in[7];
  const float* a2s  = (const float*)d_in[8];
  const float* a2d  = (const float*)d_in[9];
  const float* b2   = (const float*)d_in[10];
  const float* W3   = (const float*)d_in[11];
  const float* a3s  = (const float*)d_in[12];
  const float* a3d  = (const float*)d_in[13];
  const float* b3   = (const float*)d_in[14];
  const float* fcw  = (const float*)d_in[15];
  const float* fcb  = (const float*)d_in[16];
  float* out = (float*)d_out;

  const int N = in_sizes[0];
  const int E = in_sizes[1] / 2;
  const int Etot = E + N;
  const int dpb = N / NB;             // dst per bucket (512 for N=131072)
  int shift = 0;
  while ((1 << shift) < dpb) shift++; // log2(dpb)

  // workspace partition (256B aligned)
  char* base = (char*)d_ws;
  size_t off = 0;
  auto alloc = [&](size_t bytes) -> void* {
    void* p = base + off;
    off += (bytes + 255) & ~(size_t)255;
    return p;
  };
  unsigned short* bufB    = (unsigned short*)alloc((size_t)N * 256 * 2);  // h1 -> conv2 out -> conv3 out
  unsigned char*  buf8    = (unsigned char*)alloc((size_t)N * 256);      // h2 fp8; then h3 fp8 [N,64]
  float* alpha_s          = (float*)alloc((size_t)N * 4 * 4);
  float* alpha_d          = (float*)alloc((size_t)N * 4 * 4);
  int* row_ptr            = (int*)alloc((size_t)(N + 1) * 4);
  int* sorted_src         = (int*)alloc((size_t)Etot * 4);
  int* sorted_dst         = (int*)alloc((size_t)Etot * 4);
  float* ew               = (float*)alloc((size_t)Etot * 4 * 4);
  uint2* bbuf             = (uint2*)alloc((size_t)NB * CAP * 8);
  int* gcnt               = (int*)alloc((size_t)NB * 4);
  int* gbase              = (int*)alloc((size_t)(NB + 1) * 4);
  float* T1               = (float*)alloc(5 * 256 * 4);
  float* wt_tab           = (float*)alloc(100 * 4);
  unsigned short* Wp2     = (unsigned short*)alloc(256 * 256 * 2);
  unsigned short* Wp3     = (unsigned short*)alloc(64 * 256 * 2);

  // ---- build CSR by dst: bucket partition -> per-bucket LDS counting sort ----
  (void)hipMemsetAsync(gcnt, 0, (size_t)NB * 4, stream);
  part_k<<<(E + 4095) / 4096, 256, 0, stream>>>(ei, E, shift, gcnt, bbuf);
  bscan_k<<<1, 256, 0, stream>>>(gcnt, gbase, row_ptr, N, dpb);
  sort_k<<<NB, 256, 0, stream>>>(bbuf, gcnt, gbase, row_ptr, sorted_src, sorted_dst, dpb);

  // ---- prep: packed weights + conv1 tables (one kernel) ----
  prep_k<<<321, 256, 0, stream>>>(W2, Wp2, W3, Wp3, emb, W1, a1s, a1d, T1, wt_tab);

  // ---- conv1: histogram aggregation -> bufB [N,256] bf16 ----
  agg1_k<<<N / 256, 256, 0, stream>>>(x, T1, wt_tab, row_ptr, sorted_src, b1, bufB);

  // ---- conv2: GEMM (XCD-swizzled) -> h2 fp8 (x64) + fused head alphas ----
  gemm_lds_k<128, 1, true, true><<<(N / 128) * 2, 256, 0, stream>>>(bufB, Wp2, buf8, 256,
                                                                    a2s, a2d, alpha_s, alpha_d);
  ew4_k<<<(Etot + 255) / 256, 256, 0, stream>>>(sorted_src, sorted_dst,
                                                (const float4*)alpha_s, (const float4*)alpha_d,
                                                (float4*)ew, Etot);
  agg4_k<<<N / 4, 256, 0, stream>>>(buf8, ew, row_ptr, sorted_src, b2, bufB);

  // ---- conv3: GEMM -> h3 fp8 (x64, into buf8) + fused scalar alphas ----
  gemm_lds_k<64, 2, true, false><<<dim3(N / 128, 1), 256, 0, stream>>>(bufB, Wp3, buf8, 64,
                                                                       a3s, a3d, alpha_s, alpha_d);
  agg3_k<<<N / 4, 256, 0, stream>>>(buf8, alpha_s, alpha_d, row_ptr, sorted_src, b3, bufB);

  // ---- final FC -> d_out [N,5] f32 ----
  fc_k<<<N / 256, 256, 0, stream>>>(bufB, fcw, fcb, out);
}

// Round 18
// 355.789 us; speedup vs baseline: 1.0382x; 1.0382x over previous
//
#include <hip/hip_runtime.h>
#include <hip/hip_bf16.h>
#include <hip/hip_fp8.h>

typedef __attribute__((ext_vector_type(8))) short short8;
typedef __attribute__((ext_vector_type(4))) short short4_t;
typedef __attribute__((ext_vector_type(4))) float floatx4;
typedef __attribute__((ext_vector_type(2))) float floatx2;

constexpr int NB  = 256;    // dst buckets
constexpr int CAP = 6144;   // pairs per bucket (mean 4096 for uniform graph)

__device__ __forceinline__ unsigned short f2bf(float f){
  unsigned int u = __float_as_uint(f);
  u += 0x7FFF + ((u >> 16) & 1);           // RNE
  return (unsigned short)(u >> 16);
}
__device__ __forceinline__ float bf2f(unsigned short h){
  return __uint_as_float(((unsigned int)h) << 16);
}
__device__ __forceinline__ float lrelu(float x){ return x > 0.f ? x : 0.2f * x; }
__device__ __forceinline__ float eluf(float x){ return x > 0.f ? x : (__expf(x) - 1.f); }

__device__ __forceinline__ unsigned char f2fp8(float f){
  __hip_fp8_e4m3 t(f);
  return (unsigned char)t.__x;
}
__device__ __forceinline__ float fp82f(unsigned char b){
  __hip_fp8_e4m3 t;
  t.__x = (__hip_fp8_storage_t)b;
  return (float)t;
}

template<bool HI>
__device__ __forceinline__ floatx2 fp8pk2(unsigned int v){
#if defined(__has_builtin) && __has_builtin(__builtin_amdgcn_cvt_pk_f32_fp8)
  return __builtin_amdgcn_cvt_pk_f32_fp8((int)v, HI);
#else
  floatx2 r;
  constexpr int sh = HI ? 16 : 0;
  r.x = fp82f((unsigned char)((v >> sh) & 0xFF));
  r.y = fp82f((unsigned char)((v >> (sh + 8)) & 0xFF));
  return r;
#endif
}

// HW packed fp8 encode of 4 floats -> 4 bytes (returned in uint, b0..b3)
__device__ __forceinline__ unsigned int f32x4_to_fp8(float a0, float a1, float a2, float a3){
#if defined(__has_builtin) && __has_builtin(__builtin_amdgcn_cvt_pk_fp8_f32)
  int w = 0;
  w = __builtin_amdgcn_cvt_pk_fp8_f32(a0, a1, w, false);   // bytes 0,1
  w = __builtin_amdgcn_cvt_pk_fp8_f32(a2, a3, w, true);    // bytes 2,3
  return (unsigned int)w;
#else
  return (unsigned int)f2fp8(a0) | ((unsigned int)f2fp8(a1) << 8) |
         ((unsigned int)f2fp8(a2) << 16) | ((unsigned int)f2fp8(a3) << 24);
#endif
}

// async global->LDS, 16B per lane; LDS dest = base + lane*16
__device__ __forceinline__ void gload16(const unsigned short* g, unsigned short* l){
  __builtin_amdgcn_global_load_lds(
      (const __attribute__((address_space(1))) unsigned int*)(const void*)g,
      (__attribute__((address_space(3))) unsigned int*)(void*)l,
      16, 0, 0);
}

// ---------------- fused: edge bucket-partition + weight prep (independent work) ----------------
// blocks [0,PB): partition edges into NB dst-buckets (LDS hist, 1 global atomic/bucket)
// blocks [PB,PB+256): pack W2; [PB+256,PB+320): pack W3; PB+320: conv1 tables
__global__ __launch_bounds__(256) void part_prep_k(const int* __restrict__ ei, int E, int shift,
                                                   int* __restrict__ gcnt,
                                                   uint2* __restrict__ bbuf, int PB,
                                                   const float* __restrict__ W2,
                                                   unsigned short* __restrict__ Wp2,
                                                   const float* __restrict__ W3,
                                                   unsigned short* __restrict__ Wp3,
                                                   const float* __restrict__ emb,
                                                   const float* __restrict__ W1,
                                                   const float* __restrict__ a1s,
                                                   const float* __restrict__ a1d,
                                                   float* __restrict__ T1,
                                                   float* __restrict__ wt_tab){
  int blk = blockIdx.x;
  int tid = threadIdx.x;
  if (blk < PB){
    __shared__ int hist[NB];
    __shared__ int base[NB];
    hist[tid] = 0;
    __syncthreads();
    int blk_start = blk * 4096;
    int src[16], bkt[16], lp[16];
    #pragma unroll
    for (int k = 0; k < 16; k++){
      int i = blk_start + k * 256 + tid;
      if (i < E){
        int dst = ei[E + i];
        src[k] = ei[i];
        bkt[k] = dst >> shift;
        lp[k] = atomicAdd(&hist[bkt[k]], 1);
      } else {
        bkt[k] = -1;
      }
    }
    __syncthreads();
    base[tid] = atomicAdd(&gcnt[tid], hist[tid]);
    __syncthreads();
    #pragma unroll
    for (int k = 0; k < 16; k++){
      int i = blk_start + k * 256 + tid;
      if (i < E){
        int b = bkt[k];
        int dst = ei[E + i];              // re-read dst (L2 hot)
        bbuf[(size_t)b * CAP + base[b] + lp[k]] = make_uint2((unsigned)src[k], (unsigned)dst);
      }
    }
    return;
  }
  int b = blk - PB;
  if (b < 256){                      // W2 [256,256] -> Wp2[n*256+k]
    int idx = b * 256 + tid;
    int k = idx >> 8, nn = idx & 255;
    Wp2[nn * 256 + k] = f2bf(W2[idx]);
  } else if (b < 320){               // W3 [256,64] -> Wp3[n*256+k]
    int idx = (b - 256) * 256 + tid;
    int k = idx >> 6, nn = idx & 63;
    Wp3[nn * 256 + k] = f2bf(W3[idx]);
  } else {                           // conv1 tables
    __shared__ float t_lds[1280];
    __shared__ float as_l[20], ad_l[20];
    for (int i = tid; i < 1280; i += 256){
      int r = i >> 8, c = i & 255;
      float s = 0.f;
      for (int k = 0; k < 64; k++) s += emb[r * 64 + k] * W1[k * 256 + c];
      t_lds[i] = s;
      T1[i] = s;
    }
    __syncthreads();
    if (tid < 20){
      int r = tid >> 2, hh = tid & 3;
      float ss = 0.f, sd = 0.f;
      for (int c = 0; c < 64; c++){
        float f = t_lds[r * 256 + hh * 64 + c];
        ss += f * a1s[hh * 64 + c];
        sd += f * a1d[hh * 64 + c];
      }
      as_l[tid] = ss;
      ad_l[tid] = sd;
    }
    __syncthreads();
    if (tid < 100){
      int xd = tid / 20, rest = tid % 20;      // rest = xs*4+h
      int h = rest & 3;
      wt_tab[tid] = __expf(lrelu(as_l[rest] + ad_l[xd * 4 + h]));
    }
  }
}

__global__ __launch_bounds__(256) void bscan_k(const int* __restrict__ gcnt,
                                               int* __restrict__ gbase,
                                               int* __restrict__ row_ptr, int N, int dpb){
  __shared__ int s[NB];
  int t = threadIdx.x;
  int v = gcnt[t] + dpb;
  s[t] = v;
  __syncthreads();
  #pragma unroll
  for (int off = 1; off < NB; off <<= 1){
    int u = (t >= off) ? s[t - off] : 0;
    __syncthreads();
    s[t] += u;
    __syncthreads();
  }
  gbase[t] = s[t] - v;
  if (t == NB - 1){ gbase[NB] = s[t]; row_ptr[N] = s[t]; }
}

__global__ __launch_bounds__(256) void sort_k(const uint2* __restrict__ bbuf,
                                              const int* __restrict__ gcnt,
                                              const int* __restrict__ gbase,
                                              int* __restrict__ row_ptr,
                                              int* __restrict__ sorted_src, int dpb){
  __shared__ int counts[512];
  __shared__ int curs[512];
  __shared__ int wsum[256];
  __shared__ int sortedL[CAP + 512];
  int b = blockIdx.x, tid = threadIdx.x;
  int cnt = gcnt[b];
  int dstBase = b * dpb;
  int gb = gbase[b];
  counts[tid] = 0;
  counts[tid + 256] = 0;
  __syncthreads();
  for (int i = tid; i < cnt; i += 256){
    uint2 p = bbuf[(size_t)b * CAP + i];
    atomicAdd(&counts[(int)p.y - dstBase], 1);
  }
  __syncthreads();
  int c0 = counts[2 * tid] + 1;
  int c1 = counts[2 * tid + 1] + 1;
  int sum = c0 + c1;
  wsum[tid] = sum;
  __syncthreads();
  #pragma unroll
  for (int off = 1; off < 256; off <<= 1){
    int u = (tid >= off) ? wsum[tid - off] : 0;
    __syncthreads();
    wsum[tid] += u;
    __syncthreads();
  }
  int ex = wsum[tid] - sum;
  int ro0 = ex, ro1 = ex + c0;
  curs[2 * tid] = ro0 + 1;          // slot ro reserved for self-loop
  curs[2 * tid + 1] = ro1 + 1;
  sortedL[ro0] = dstBase + 2 * tid;
  sortedL[ro1] = dstBase + 2 * tid + 1;
  row_ptr[dstBase + 2 * tid] = gb + ro0;
  row_ptr[dstBase + 2 * tid + 1] = gb + ro1;
  __syncthreads();
  for (int i = tid; i < cnt; i += 256){
    uint2 p = bbuf[(size_t)b * CAP + i];
    int pos = atomicAdd(&curs[(int)p.y - dstBase], 1);
    sortedL[pos] = (int)p.x;
  }
  __syncthreads();
  int tot = cnt + dpb;
  for (int i = tid; i < tot; i += 256) sorted_src[gb + i] = sortedL[i];
}

// ---------------- LDS-staged MFMA GEMM, fused alpha epilogues ----------------
// MODE 1 (BN=128): per-head alpha. MODE 2 (BN=64): scalar alpha.
// F8OUT: C written as fp8 e4m3 scaled x64.
template<int BN, int MODE, bool F8OUT>
__global__ __launch_bounds__(256) void gemm_lds_k(const unsigned short* __restrict__ A,
                                                  const unsigned short* __restrict__ Wp,
                                                  void* __restrict__ Cout, int Nc,
                                                  const float* __restrict__ a_src,
                                                  const float* __restrict__ a_dst,
                                                  float* __restrict__ as_arr,
                                                  float* __restrict__ ad_arr){
  constexpr int K = 256;
  constexpr int NT = BN / 32;               // col tiles per wave (4 or 2)
  __shared__ unsigned short Alds[128 * 32];
  __shared__ unsigned short Blds[BN * 32];
  __shared__ float asl[128], adl[128];
  __shared__ float pas[128][2], pad[128][2];
  int tid = threadIdx.x;
  int w = tid >> 6, l = tid & 63;
  int r16 = l & 15, quad = l >> 4;
  int wr = w >> 1, wc = w & 1;
  int mBase = blockIdx.x * 128;
  int nBase = blockIdx.y * BN;

  if constexpr (MODE == 1){
    if (tid < 128){ asl[tid] = a_src[nBase + tid]; adl[tid] = a_dst[nBase + tid]; }
  }
  if constexpr (MODE == 2){
    if (tid < 64){ asl[tid] = a_src[tid]; adl[tid] = a_dst[tid]; }
  }

  int arow = l >> 2;
  int kcol = (l & 3) * 8;                   // shorts
  const unsigned short* gA0 = A + (size_t)(mBase + w * 32 + arow) * K + kcol;
  const unsigned short* gA1 = gA0 + (size_t)16 * K;
  unsigned short* lA0 = &Alds[(w * 32) * 32];
  unsigned short* lA1 = &Alds[(w * 32 + 16) * 32];
  const unsigned short* gB0;
  const unsigned short* gB1 = nullptr;
  unsigned short* lB0;
  unsigned short* lB1 = nullptr;
  if constexpr (BN == 128){
    gB0 = Wp + (size_t)(nBase + w * 32 + arow) * K + kcol;
    gB1 = gB0 + (size_t)16 * K;
    lB0 = &Blds[(w * 32) * 32];
    lB1 = &Blds[(w * 32 + 16) * 32];
  } else {
    gB0 = Wp + (size_t)(nBase + w * 16 + arow) * K + kcol;
    lB0 = &Blds[(w * 16) * 32];
  }

  floatx4 acc[4][NT];
  #pragma unroll
  for (int mt = 0; mt < 4; mt++)
    #pragma unroll
    for (int nt = 0; nt < NT; nt++){ floatx4 z = {0.f,0.f,0.f,0.f}; acc[mt][nt] = z; }

  for (int kt = 0; kt < 8; kt++){
    int ko = kt * 32;
    gload16(gA0 + ko, lA0);
    gload16(gA1 + ko, lA1);
    gload16(gB0 + ko, lB0);
    if constexpr (BN == 128) gload16(gB1 + ko, lB1);
    __syncthreads();
    short8 af[4], bfr[NT];
    #pragma unroll
    for (int mt = 0; mt < 4; mt++)
      af[mt] = *(const short8*)&Alds[(wr * 64 + mt * 16 + r16) * 32 + quad * 8];
    #pragma unroll
    for (int nt = 0; nt < NT; nt++)
      bfr[nt] = *(const short8*)&Blds[(wc * (BN / 2) + nt * 16 + r16) * 32 + quad * 8];
    #pragma unroll
    for (int mt = 0; mt < 4; mt++)
      #pragma unroll
      for (int nt = 0; nt < NT; nt++)
        acc[mt][nt] = __builtin_amdgcn_mfma_f32_16x16x32_bf16(af[mt], bfr[nt], acc[mt][nt], 0, 0, 0);
    __syncthreads();
  }

  // epilogue: C/D layout col=lane&15, row=quad*4+reg
  #pragma unroll
  for (int mt = 0; mt < 4; mt++){
    #pragma unroll
    for (int nt = 0; nt < NT; nt++){
      if constexpr (F8OUT){
        unsigned int pk = f32x4_to_fp8(acc[mt][nt][0] * 64.f, acc[mt][nt][1] * 64.f,
                                       acc[mt][nt][2] * 64.f, acc[mt][nt][3] * 64.f);
        int col = nBase + wc * (BN / 2) + nt * 16 + r16;
        int row0 = mBase + wr * 64 + mt * 16 + quad * 4;
        #pragma unroll
        for (int r = 0; r < 4; r++)
          ((unsigned char*)Cout)[(size_t)(row0 + r) * Nc + col] =
              (unsigned char)((pk >> (r * 8)) & 0xFF);
      } else {
        #pragma unroll
        for (int r = 0; r < 4; r++){
          int row = mBase + wr * 64 + mt * 16 + quad * 4 + r;
          int col = nBase + wc * (BN / 2) + nt * 16 + r16;
          ((unsigned short*)Cout)[(size_t)row * Nc + col] = f2bf(acc[mt][nt][r]);
        }
      }
    }
  }
  if constexpr (MODE == 1){
    int head = (nBase + wc * 64) >> 6;
    #pragma unroll
    for (int mt = 0; mt < 4; mt++){
      #pragma unroll
      for (int r = 0; r < 4; r++){
        float ps = 0.f, pd = 0.f;
        #pragma unroll
        for (int nt = 0; nt < NT; nt++){
          float v = acc[mt][nt][r];
          int ci = wc * 64 + nt * 16 + r16;
          ps += v * asl[ci];
          pd += v * adl[ci];
        }
        ps += __shfl_xor(ps, 1, 64); ps += __shfl_xor(ps, 2, 64);
        ps += __shfl_xor(ps, 4, 64); ps += __shfl_xor(ps, 8, 64);
        pd += __shfl_xor(pd, 1, 64); pd += __shfl_xor(pd, 2, 64);
        pd += __shfl_xor(pd, 4, 64); pd += __shfl_xor(pd, 8, 64);
        if (r16 == 0){
          int row = mBase + wr * 64 + mt * 16 + quad * 4 + r;
          as_arr[row * 4 + head] = ps;
          ad_arr[row * 4 + head] = pd;
        }
      }
    }
  }
  if constexpr (MODE == 2){
    #pragma unroll
    for (int mt = 0; mt < 4; mt++){
      #pragma unroll
      for (int r = 0; r < 4; r++){
        float ps = 0.f, pd = 0.f;
        #pragma unroll
        for (int nt = 0; nt < NT; nt++){
          float v = acc[mt][nt][r];
          int ci = wc * 32 + nt * 16 + r16;
          ps += v * asl[ci];
          pd += v * adl[ci];
        }
        ps += __shfl_xor(ps, 1, 64); ps += __shfl_xor(ps, 2, 64);
        ps += __shfl_xor(ps, 4, 64); ps += __shfl_xor(ps, 8, 64);
        pd += __shfl_xor(pd, 1, 64); pd += __shfl_xor(pd, 2, 64);
        pd += __shfl_xor(pd, 4, 64); pd += __shfl_xor(pd, 8, 64);
        if (r16 == 0){
          int lr = wr * 64 + mt * 16 + quad * 4 + r;
          pas[lr][wc] = ps;
          pad[lr][wc] = pd;
        }
      }
    }
    __syncthreads();
    if (tid < 128){
      as_arr[mBase + tid] = pas[tid][0] + pas[tid][1];
      ad_arr[mBase + tid] = pad[tid][0] + pad[tid][1];
    }
  }
}

// ---------------- conv1 aggregation: 5-bin neighbor-value histogram ----------------

__global__ __launch_bounds__(256) void agg1_k(const int* __restrict__ x,
                                              const float* __restrict__ T1,
                                              const float* __restrict__ wt_tab,
                                              const int* __restrict__ row_ptr,
                                              const int* __restrict__ sorted_src,
                                              const float* __restrict__ bias,
                                              unsigned short* __restrict__ outb){
  __shared__ float t_lds[1280];
  __shared__ float wt_l[100], b_lds[256];
  __shared__ float cnt_lds[256][5];
  __shared__ int xd_lds[256];
  int tid = threadIdx.x;
  for (int i = tid; i < 1280; i += 256) t_lds[i] = T1[i];
  if (tid < 100) wt_l[tid] = wt_tab[tid];
  b_lds[tid] = bias[tid];
  // phase 1: histogram
  int d = blockIdx.x * 256 + tid;
  int start = row_ptr[d], end = row_ptr[d + 1];
  xd_lds[tid] = x[d];
  float c0 = 0.f, c1 = 0.f, c2 = 0.f, c3 = 0.f, c4 = 0.f;
  for (int e = start; e < end; e++){
    int xs = x[sorted_src[e]];
    c0 += (xs == 0) ? 1.f : 0.f;
    c1 += (xs == 1) ? 1.f : 0.f;
    c2 += (xs == 2) ? 1.f : 0.f;
    c3 += (xs == 3) ? 1.f : 0.f;
    c4 += (xs == 4) ? 1.f : 0.f;
  }
  cnt_lds[tid][0] = c0; cnt_lds[tid][1] = c1; cnt_lds[tid][2] = c2;
  cnt_lds[tid][3] = c3; cnt_lds[tid][4] = c4;
  __syncthreads();
  // phase 2: wave per dst, lane covers 4 channels
  int w = tid >> 6, l = tid & 63;
  int head = l >> 4;
  int c0i = l * 4;
  for (int dl = w; dl < 256; dl += 4){
    int dd = blockIdx.x * 256 + dl;
    int xd20 = xd_lds[dl] * 20;
    float ws[5];
    float den = 0.f;
    #pragma unroll
    for (int v2 = 0; v2 < 5; v2++){
      float wv = wt_l[xd20 + v2 * 4 + head] * cnt_lds[dl][v2];
      ws[v2] = wv;
      den += wv;
    }
    float inv = 1.f / (den + 1e-16f);
    float num[4] = {0.f, 0.f, 0.f, 0.f};
    #pragma unroll
    for (int v2 = 0; v2 < 5; v2++){
      const float4 row = *(const float4*)&t_lds[v2 * 256 + c0i];
      num[0] += ws[v2] * row.x;
      num[1] += ws[v2] * row.y;
      num[2] += ws[v2] * row.z;
      num[3] += ws[v2] * row.w;
    }
    short4_t ov;
    #pragma unroll
    for (int j = 0; j < 4; j++)
      ov[j] = (short)f2bf(eluf(num[j] * inv + b_lds[c0i + j]));
    *(short4_t*)(outb + (size_t)dd * 256 + c0i) = ov;
  }
}

// ---------------- conv2 aggregation: 4-deep unrolled gather, fp8 payload ----------------

__global__ __launch_bounds__(256) void agg4_k(const unsigned char* __restrict__ h8,
                                              const float* __restrict__ as_arr,
                                              const float* __restrict__ ad_arr,
                                              const int* __restrict__ row_ptr,
                                              const int* __restrict__ sorted_src,
                                              const float* __restrict__ bias,
                                              unsigned short* __restrict__ outb){
  __shared__ float b_lds[256];
  int tid = threadIdx.x;
  b_lds[tid] = bias[tid];
  __syncthreads();
  int w = tid >> 6, l = tid & 63;
  int d = blockIdx.x * 4 + w;
  int hl = l & 31, half = l >> 5;
  unsigned head = (unsigned)(hl >> 3);
  unsigned hloff = (unsigned)(hl * 8);
  int start = row_ptr[d], end = row_ptr[d + 1];
  float a_d = ad_arr[d * 4 + head];
  floatx2 ac0 = {0.f, 0.f}, ac1 = {0.f, 0.f}, ac2 = {0.f, 0.f}, ac3 = {0.f, 0.f};
  float den = 0.f;
  int e = start + half;
  for (; e + 6 < end; e += 8){
    unsigned sA = (unsigned)sorted_src[e];
    unsigned sB = (unsigned)sorted_src[e + 2];
    unsigned sC = (unsigned)sorted_src[e + 4];
    unsigned sD = (unsigned)sorted_src[e + 6];
    uint2 vA = *(const uint2*)(h8 + ((sA << 8) | hloff));
    uint2 vB = *(const uint2*)(h8 + ((sB << 8) | hloff));
    uint2 vC = *(const uint2*)(h8 + ((sC << 8) | hloff));
    uint2 vD = *(const uint2*)(h8 + ((sD << 8) | hloff));
    float wgA = __expf(lrelu(as_arr[(sA << 2) + head] + a_d));
    float wgB = __expf(lrelu(as_arr[(sB << 2) + head] + a_d));
    float wgC = __expf(lrelu(as_arr[(sC << 2) + head] + a_d));
    float wgD = __expf(lrelu(as_arr[(sD << 2) + head] + a_d));
    den += (wgA + wgB) + (wgC + wgD);
    floatx2 wA = {wgA, wgA}, wB = {wgB, wgB}, wC = {wgC, wgC}, wD = {wgD, wgD};
    ac0 += wA * fp8pk2<false>(vA.x) + wB * fp8pk2<false>(vB.x)
         + wC * fp8pk2<false>(vC.x) + wD * fp8pk2<false>(vD.x);
    ac1 += wA * fp8pk2<true>(vA.x)  + wB * fp8pk2<true>(vB.x)
         + wC * fp8pk2<true>(vC.x)  + wD * fp8pk2<true>(vD.x);
    ac2 += wA * fp8pk2<false>(vA.y) + wB * fp8pk2<false>(vB.y)
         + wC * fp8pk2<false>(vC.y) + wD * fp8pk2<false>(vD.y);
    ac3 += wA * fp8pk2<true>(vA.y)  + wB * fp8pk2<true>(vB.y)
         + wC * fp8pk2<true>(vC.y)  + wD * fp8pk2<true>(vD.y);
  }
  for (; e + 2 < end; e += 4){
    unsigned sA = (unsigned)sorted_src[e];
    unsigned sB = (unsigned)sorted_src[e + 2];
    uint2 vA = *(const uint2*)(h8 + ((sA << 8) | hloff));
    uint2 vB = *(const uint2*)(h8 + ((sB << 8) | hloff));
    float wgA = __expf(lrelu(as_arr[(sA << 2) + head] + a_d));
    float wgB = __expf(lrelu(as_arr[(sB << 2) + head] + a_d));
    den += wgA + wgB;
    floatx2 wA = {wgA, wgA}, wB = {wgB, wgB};
    ac0 += wA * fp8pk2<false>(vA.x) + wB * fp8pk2<false>(vB.x);
    ac1 += wA * fp8pk2<true>(vA.x)  + wB * fp8pk2<true>(vB.x);
    ac2 += wA * fp8pk2<false>(vA.y) + wB * fp8pk2<false>(vB.y);
    ac3 += wA * fp8pk2<true>(vA.y)  + wB * fp8pk2<true>(vB.y);
  }
  for (; e < end; e += 2){
    unsigned s = (unsigned)sorted_src[e];
    float wg = __expf(lrelu(as_arr[(s << 2) + head] + a_d));
    den += wg;
    uint2 v = *(const uint2*)(h8 + ((s << 8) | hloff));
    floatx2 wv = {wg, wg};
    ac0 += wv * fp8pk2<false>(v.x);
    ac1 += wv * fp8pk2<true>(v.x);
    ac2 += wv * fp8pk2<false>(v.y);
    ac3 += wv * fp8pk2<true>(v.y);
  }
  float acc[8] = {ac0.x, ac0.y, ac1.x, ac1.y, ac2.x, ac2.y, ac3.x, ac3.y};
  #pragma unroll
  for (int j = 0; j < 8; j++) acc[j] += __shfl_xor(acc[j], 32, 64);
  den += __shfl_xor(den, 32, 64);
  if (half == 0){
    float inv = 0.015625f / (den + 1e-16f);    // 1/64 undoes fp8 pre-scale
    short8 ov;
    #pragma unroll
    for (int j = 0; j < 8; j++){
      float v = eluf(acc[j] * inv + b_lds[hl * 8 + j]);
      ov[j] = (short)f2bf(v);
    }
    *(short8*)(outb + (size_t)d * 256 + hl * 8) = ov;
  }
}

// ---------------- conv3 aggregation (H=1): fp8 payload, eighth-wave per edge ----------------

__global__ __launch_bounds__(256) void agg3_k(const unsigned char* __restrict__ h8,
                                              const float* __restrict__ as_arr,
                                              const float* __restrict__ ad_arr,
                                              const int* __restrict__ row_ptr,
                                              const int* __restrict__ sorted_src,
                                              const float* __restrict__ bias,
                                              unsigned short* __restrict__ outb){
  __shared__ float b_lds[64];
  int tid = threadIdx.x;
  if (tid < 64) b_lds[tid] = bias[tid];
  __syncthreads();
  int w = tid >> 6, l = tid & 63;
  int d = blockIdx.x * 4 + w;
  int q = l & 7, grp = l >> 3;          // 8 groups of 8 lanes
  unsigned qoff = (unsigned)(q * 8);    // 8 bytes per lane
  int start = row_ptr[d], end = row_ptr[d + 1];
  float a_d = ad_arr[d];
  floatx2 ac0 = {0.f, 0.f}, ac1 = {0.f, 0.f}, ac2 = {0.f, 0.f}, ac3 = {0.f, 0.f};
  float den = 0.f;
  int e = start + grp;
  for (; e + 8 < end; e += 16){
    unsigned sA = (unsigned)sorted_src[e];
    unsigned sB = (unsigned)sorted_src[e + 8];
    uint2 vA = *(const uint2*)(h8 + ((sA << 6) | qoff));
    uint2 vB = *(const uint2*)(h8 + ((sB << 6) | qoff));
    float wgA = __expf(lrelu(as_arr[sA] + a_d));
    float wgB = __expf(lrelu(as_arr[sB] + a_d));
    den += wgA + wgB;
    floatx2 wA = {wgA, wgA}, wB = {wgB, wgB};
    ac0 += wA * fp8pk2<false>(vA.x) + wB * fp8pk2<false>(vB.x);
    ac1 += wA * fp8pk2<true>(vA.x)  + wB * fp8pk2<true>(vB.x);
    ac2 += wA * fp8pk2<false>(vA.y) + wB * fp8pk2<false>(vB.y);
    ac3 += wA * fp8pk2<true>(vA.y)  + wB * fp8pk2<true>(vB.y);
  }
  for (; e < end; e += 8){
    unsigned s = (unsigned)sorted_src[e];
    float wg = __expf(lrelu(as_arr[s] + a_d));
    den += wg;
    uint2 v = *(const uint2*)(h8 + ((s << 6) | qoff));
    floatx2 wv = {wg, wg};
    ac0 += wv * fp8pk2<false>(v.x);
    ac1 += wv * fp8pk2<true>(v.x);
    ac2 += wv * fp8pk2<false>(v.y);
    ac3 += wv * fp8pk2<true>(v.y);
  }
  float acc[8] = {ac0.x, ac0.y, ac1.x, ac1.y, ac2.x, ac2.y, ac3.x, ac3.y};
  #pragma unroll
  for (int j = 0; j < 8; j++){
    acc[j] += __shfl_xor(acc[j], 8, 64);
    acc[j] += __shfl_xor(acc[j], 16, 64);
    acc[j] += __shfl_xor(acc[j], 32, 64);
  }
  den += __shfl_xor(den, 8, 64);
  den += __shfl_xor(den, 16, 64);
  den += __shfl_xor(den, 32, 64);
  if (l < 8){
    float inv = 0.015625f / (den + 1e-16f);    // 1/64 undoes fp8 pre-scale
    short8 ov;
    #pragma unroll
    for (int j = 0; j < 8; j++){
      float v = eluf(acc[j] * inv + b_lds[q * 8 + j]);
      ov[j] = (short)f2bf(v);
    }
    *(short8*)(outb + (size_t)d * 64 + q * 8) = ov;
  }
}

// ---------------- final FC: out[N,5] = h[N,64] @ fc_w + fc_b ----------------

__global__ __launch_bounds__(256) void fc_k(const unsigned short* __restrict__ hb,
                                            const float* __restrict__ fcw,
                                            const float* __restrict__ fcb,
                                            float* __restrict__ out){
  __shared__ float w_lds[320];
  __shared__ float b_lds[5];
  int tid = threadIdx.x;
  for (int i = tid; i < 320; i += 256) w_lds[i] = fcw[i];
  if (tid < 5) b_lds[tid] = fcb[tid];
  __syncthreads();
  int n = blockIdx.x * 256 + tid;
  const short8* p = (const short8*)(hb + (size_t)n * 64);
  float acc[5];
  #pragma unroll
  for (int j = 0; j < 5; j++) acc[j] = b_lds[j];
  #pragma unroll
  for (int b = 0; b < 8; b++){
    short8 v = p[b];
    #pragma unroll
    for (int j8 = 0; j8 < 8; j8++){
      float f = bf2f((unsigned short)v[j8]);
      int k = b * 8 + j8;
      #pragma unroll
      for (int j = 0; j < 5; j++) acc[j] += f * w_lds[k * 5 + j];
    }
  }
  #pragma unroll
  for (int j = 0; j < 5; j++) out[(size_t)n * 5 + j] = acc[j];
}

// ---------------- host launch ----------------

extern "C" void kernel_launch(void* const* d_in, const int* in_sizes, int n_in,
                              void* d_out, int out_size, void* d_ws, size_t ws_size,
                              hipStream_t stream){
  const int*   x    = (const int*)d_in[0];
  const int*   ei   = (const int*)d_in[1];
  const float* emb  = (const float*)d_in[2];
  const float* W1   = (const float*)d_in[3];
  const float* a1s  = (const float*)d_in[4];
  const float* a1d  = (const float*)d_in[5];
  const float* b1   = (const float*)d_in[6];
  const float* W2   = (const float*)d_in[7];
  const float* a2s  = (const float*)d_in[8];
  const float* a2d  = (const float*)d_in[9];
  const float* b2   = (const float*)d_in[10];
  const float* W3   = (const float*)d_in[11];
  const float* a3s  = (const float*)d_in[12];
  const float* a3d  = (const float*)d_in[13];
  const float* b3   = (const float*)d_in[14];
  const float* fcw  = (const float*)d_in[15];
  const float* fcb  = (const float*)d_in[16];
  float* out = (float*)d_out;

  const int N = in_sizes[0];
  const int E = in_sizes[1] / 2;
  const int dpb = N / NB;             // dst per bucket (512 for N=131072)
  int shift = 0;
  while ((1 << shift) < dpb) shift++; // log2(dpb)
  const int PB = (E + 4095) / 4096;   // partition blocks

  // workspace partition (256B aligned)
  char* base = (char*)d_ws;
  size_t off = 0;
  auto alloc = [&](size_t bytes) -> void* {
    void* p = base + off;
    off += (bytes + 255) & ~(size_t)255;
    return p;
  };
  unsigned short* bufB    = (unsigned short*)alloc((size_t)N * 256 * 2);  // h1 -> conv2 out -> conv3 out
  unsigned char*  buf8    = (unsigned char*)alloc((size_t)N * 256);      // h2 fp8; then h3 fp8 [N,64]
  float* alpha_s          = (float*)alloc((size_t)N * 4 * 4);
  float* alpha_d          = (float*)alloc((size_t)N * 4 * 4);
  int* row_ptr            = (int*)alloc((size_t)(N + 1) * 4);
  int* sorted_src         = (int*)alloc((size_t)(E + N) * 4);
  uint2* bbuf             = (uint2*)alloc((size_t)NB * CAP * 8);
  int* gcnt               = (int*)alloc((size_t)NB * 4);
  int* gbase              = (int*)alloc((size_t)(NB + 1) * 4);
  float* T1               = (float*)alloc(5 * 256 * 4);
  float* wt_tab           = (float*)alloc(100 * 4);
  unsigned short* Wp2     = (unsigned short*)alloc(256 * 256 * 2);
  unsigned short* Wp3     = (unsigned short*)alloc(64 * 256 * 2);

  // ---- CSR build (bucket partition) + weight prep, fused ----
  (void)hipMemsetAsync(gcnt, 0, (size_t)NB * 4, stream);
  part_prep_k<<<PB + 321, 256, 0, stream>>>(ei, E, shift, gcnt, bbuf, PB,
                                            W2, Wp2, W3, Wp3, emb, W1, a1s, a1d, T1, wt_tab);
  bscan_k<<<1, 256, 0, stream>>>(gcnt, gbase, row_ptr, N, dpb);
  sort_k<<<NB, 256, 0, stream>>>(bbuf, gcnt, gbase, row_ptr, sorted_src, dpb);

  // ---- conv1: histogram aggregation -> bufB [N,256] bf16 ----
  agg1_k<<<N / 256, 256, 0, stream>>>(x, T1, wt_tab, row_ptr, sorted_src, b1, bufB);

  // ---- conv2: GEMM -> h2 fp8 (x64) + fused head alphas; aggregate -> bufB ----
  gemm_lds_k<128, 1, true><<<dim3(N / 128, 2), 256, 0, stream>>>(bufB, Wp2, buf8, 256,
                                                                 a2s, a2d, alpha_s, alpha_d);
  agg4_k<<<N / 4, 256, 0, stream>>>(buf8, alpha_s, alpha_d, row_ptr, sorted_src, b2, bufB);

  // ---- conv3: GEMM -> h3 fp8 (x64, into buf8) + fused scalar alphas ----
  gemm_lds_k<64, 2, true><<<dim3(N / 128, 1), 256, 0, stream>>>(bufB, Wp3, buf8, 64,
                                                                a3s, a3d, alpha_s, alpha_d);
  agg3_k<<<N / 4, 256, 0, stream>>>(buf8, alpha_s, alpha_d, row_ptr, sorted_src, b3, bufB);

  // ---- final FC -> d_out [N,5] f32 ----
  fc_k<<<N / 256, 256, 0, stream>>>(bufB, fcw, fcb, out);
}